// Round 5
// baseline (673.317 us; speedup 1.0000x reference)
//
#include <hip/hip_runtime.h>

// Problem constants
// N=8, T_y=300, T_x=160, E=256, E/2=128, 3E=768
// d_out: [attn 8*300*160 = 384000][outputs 8*300*256 = 614400][hidden 2048]

typedef _Float16 f16x2 __attribute__((ext_vector_type(2)));
typedef _Float16 f16x8 __attribute__((ext_vector_type(8)));

__device__ __forceinline__ float fexp2(float x) { return __builtin_amdgcn_exp2f(x); }
__device__ __forceinline__ float frcp(float x) { return __builtin_amdgcn_rcpf(x); }
// sigmoid(x) = 1/(1+2^(-x*log2 e))
__device__ __forceinline__ float fsig(float x) {
    return frcp(1.0f + fexp2(x * -1.4426950408889634f));
}
// tanh(y) = 1 - 2/(1+2^(y*2*log2 e)); saturates correctly at +-inf args
__device__ __forceinline__ float ftanh(float x) {
    return 1.0f - 2.0f * frcp(1.0f + fexp2(x * 2.8853900817779268f));
}

__device__ __forceinline__ f16x2 bc_h2(unsigned u) {
    union { unsigned u; f16x2 h; } cv;
    cv.u = u;
    return cv.h;
}

// Permuted LDS index for hidden unit j: cc-major so that a quad's four
// k-quarter chunks for the same cc land in different banks.
// j = qi*64 + cc*8 + off  ->  phys = cc*32 + qi*8 + off.
__device__ __forceinline__ int hperm(int j) {
    return ((j >> 3) & 7) * 32 + (j >> 6) * 8 + (j & 7);
}

// ---------------------------------------------------------------------------
// Kernel A: repack Whh (f32 [768][256]) into per-thread v_dot2 weight order.
// gru thread t (of 1024): quad qd=t>>2 owns hidden unit qd's three gate rows
// {qd, qd+256, qd+512}; lane qi=t&3 owns k-quarter [qi*64, qi*64+64).
// Consumption order i = cc*12 + rr*4 + m, cc in [0,8): chunk of 8 f16 at
// k = qi*64 + cc*8; rr = gate row; m = f16x2 within chunk (k+2m).
// wd layout [i*1024 + t] so the one-time gru load is coalesced.
// ---------------------------------------------------------------------------
__global__ __launch_bounds__(256) void prep_wd(const float* __restrict__ Whh,
                                               unsigned* __restrict__ wd) {
    int gid = blockIdx.x * 256 + threadIdx.x;   // 0..98303 = 96*1024
    int i = gid >> 10, t = gid & 1023;
    int qd = t >> 2, qi = t & 3;
    int cc = i / 12, rem = i - cc * 12;
    int rr = rem >> 2, m = rem & 3;
    int row = qd + rr * 256;
    int k = qi * 64 + cc * 8 + 2 * m;
    union { unsigned u; f16x2 h; } cv;
    cv.h[0] = (_Float16)Whh[(size_t)row * 256 + k];
    cv.h[1] = (_Float16)Whh[(size_t)row * 256 + k + 1];
    wd[i * 1024 + t] = cv.u;
}

// ---------------------------------------------------------------------------
// Kernel B: generic f32 tiled GEMM  C[M,N] = X[M,K] @ Wt[N,K]^T
// mode 0: C f32 natural [row*N+col]
// mode 1: gi scatter: row=(b*300+t) -> store at (t*8+b)*768+col, bias folded
//         (bih+bhh for r,z gates; bih only for n gate)
// mode 2: C16 f16 natural
// BM=BN=64, BK=32, 256 threads, 4x4 per thread.
// ---------------------------------------------------------------------------
__global__ __launch_bounds__(256) void gemm_kernel(
    const float* __restrict__ X, const float* __restrict__ Wt,
    float* __restrict__ C, _Float16* __restrict__ C16,
    const float* __restrict__ bih, const float* __restrict__ bhh,
    int M, int N, int K, int mode) {
    __shared__ float Xs[32][65];
    __shared__ float Ws2[32][65];
    const int n0 = blockIdx.x * 64, m0 = blockIdx.y * 64;
    const int tid = threadIdx.x;
    const int tx = tid & 15, ty = tid >> 4;
    float acc[4][4] = {};
    for (int k0 = 0; k0 < K; k0 += 32) {
#pragma unroll
        for (int i = 0; i < 8; ++i) {
            int e = tid + i * 256;
            int kk = e & 31, m = e >> 5;
            int row = m0 + m;
            Xs[kk][m] = (row < M) ? X[(size_t)row * K + k0 + kk] : 0.0f;
            Ws2[kk][m] = Wt[(size_t)(n0 + m) * K + k0 + kk];
        }
        __syncthreads();
#pragma unroll
        for (int kk = 0; kk < 32; ++kk) {
            float a[4], b[4];
#pragma unroll
            for (int i = 0; i < 4; ++i) a[i] = Xs[kk][ty * 4 + i];
#pragma unroll
            for (int j = 0; j < 4; ++j) b[j] = Ws2[kk][tx * 4 + j];
#pragma unroll
            for (int i = 0; i < 4; ++i)
#pragma unroll
                for (int j = 0; j < 4; ++j) acc[i][j] += a[i] * b[j];
        }
        __syncthreads();
    }
#pragma unroll
    for (int i = 0; i < 4; ++i) {
        int row = m0 + ty * 4 + i;
        if (row >= M) continue;
#pragma unroll
        for (int j = 0; j < 4; ++j) {
            int col = n0 + tx * 4 + j;
            float val = acc[i][j];
            if (mode == 1) {
                int b = row / 300;
                int t = row - b * 300;
                val += (col < 512) ? (bih[col] + bhh[col]) : bih[col];
                C[(size_t)(t * 8 + b) * 768 + col] = val;
            } else if (mode == 2) {
                C16[(size_t)row * N + col] = (_Float16)val;
            } else {
                C[(size_t)row * N + col] = val;
            }
        }
    }
}

// ---------------------------------------------------------------------------
// Kernel C: GRU recurrence via v_dot2_f32_f16, weights resident in VGPRs.
// 8 blocks (one per batch) x 1024 threads (16 waves = 4 waves/EU -> HW caps
// VGPRs at 128, which COINCIDES with the backend's observed occupancy
// target; 96 weight words + ~25 temps fit -> no spill, unlike the 512-thr
// 192-word design the allocator kept streaming (rounds 1/3/4: VGPR 116-124,
// ~2700 cy/step)).
// Quad qd = t>>2 owns hidden unit qd's rows {qd, qd+256, qd+512}; lane
// qi = t&3 owns k-quarter [qi*64,+64). After a 2-step shfl_xor quad
// butterfly every lane holds (gh_r, gh_z, gh_n) for unit qd -> epilogue is
// computed in-register (4x redundant), no gh LDS buffer, ONE barrier/step.
// h lives in LDS f16, double-buffered, in hperm() layout so the quad's four
// chunk reads per cc are bank-disjoint (kills the 1.23M conflict cycles).
// Issue floor: 96 dot2 x 4 waves x 2cy = 768 cy/SIMD/step.
// ---------------------------------------------------------------------------
__global__ __launch_bounds__(1024)
__attribute__((amdgpu_waves_per_eu(4, 4)))
void gru_kernel(
    const float* __restrict__ gi, const unsigned* __restrict__ wd,
    const float* __restrict__ h0, const float* __restrict__ bhh,
    float* __restrict__ outs, float* __restrict__ hid) {
    const int b = blockIdx.x;
    const int t = threadIdx.x;
    const int qd = t >> 2, qi = t & 3;

    __shared__ __align__(16) _Float16 hbuf[2][256];

    // One-time resident weight load (coalesced): 96 VGPRs/thread.
    unsigned w[96];
#pragma unroll
    for (int i = 0; i < 96; ++i) w[i] = wd[i * 1024 + t];

    float h = h0[b * 256 + qd];
    const float bn = bhh[512 + qd];   // bhh_n stays inside r*(.)
    const int ph = hperm(qd);
    if (t < 256) hbuf[0][hperm(t)] = (_Float16)h0[b * 256 + t];

    const float* gp = gi + b * 768 + qd;
    float* op = outs + (size_t)b * 76800 + qd;
    __syncthreads();

    for (int st = 0; st < 300; ++st) {
        // gi prefetch (independent of dot2 chain; scheduled early)
        const float* g = gp + (size_t)st * 6144;
        float gr = g[0], gz = g[256], gn = g[512];

        const _Float16* hb = hbuf[st & 1];
        float s0 = 0.f, s1 = 0.f, s2 = 0.f;
#pragma unroll
        for (int cc = 0; cc < 8; ++cc) {
            f16x8 hv = *(const f16x8*)(hb + cc * 32 + qi * 8);  // bank-disjoint
            f16x2 p0 = {hv[0], hv[1]}, p1 = {hv[2], hv[3]};
            f16x2 p2 = {hv[4], hv[5]}, p3 = {hv[6], hv[7]};
            s0 = __builtin_amdgcn_fdot2(bc_h2(w[cc * 12 + 0]), p0, s0, false);
            s0 = __builtin_amdgcn_fdot2(bc_h2(w[cc * 12 + 1]), p1, s0, false);
            s0 = __builtin_amdgcn_fdot2(bc_h2(w[cc * 12 + 2]), p2, s0, false);
            s0 = __builtin_amdgcn_fdot2(bc_h2(w[cc * 12 + 3]), p3, s0, false);
            s1 = __builtin_amdgcn_fdot2(bc_h2(w[cc * 12 + 4]), p0, s1, false);
            s1 = __builtin_amdgcn_fdot2(bc_h2(w[cc * 12 + 5]), p1, s1, false);
            s1 = __builtin_amdgcn_fdot2(bc_h2(w[cc * 12 + 6]), p2, s1, false);
            s1 = __builtin_amdgcn_fdot2(bc_h2(w[cc * 12 + 7]), p3, s1, false);
            s2 = __builtin_amdgcn_fdot2(bc_h2(w[cc * 12 + 8]), p0, s2, false);
            s2 = __builtin_amdgcn_fdot2(bc_h2(w[cc * 12 + 9]), p1, s2, false);
            s2 = __builtin_amdgcn_fdot2(bc_h2(w[cc * 12 + 10]), p2, s2, false);
            s2 = __builtin_amdgcn_fdot2(bc_h2(w[cc * 12 + 11]), p3, s2, false);
        }
        // Quad butterfly: total over the four k-quarters.
        s0 += __shfl_xor(s0, 1); s0 += __shfl_xor(s0, 2);
        s1 += __shfl_xor(s1, 1); s1 += __shfl_xor(s1, 2);
        s2 += __shfl_xor(s2, 1); s2 += __shfl_xor(s2, 2);
        // In-register epilogue (all 4 quad lanes redundantly).
        float r = fsig(gr + s0);
        float z = fsig(gz + s1);
        float n = ftanh(gn + r * (s2 + bn));
        h = n + z * (h - n);
        if (qi == 0) hbuf[(st + 1) & 1][ph] = (_Float16)h;
        else if (qi == 1) op[st * 256] = h;
        __syncthreads();
    }
    if (qi == 2) hid[b * 256 + qd] = h;
}

// ---------------------------------------------------------------------------
// Kernel D: scores + softmax. Block = (t-chunk of 10, batch). Threads 0..159
// each own one x; u read as f16 from ws, w-row and v staged in LDS.
// ---------------------------------------------------------------------------
__global__ __launch_bounds__(256) void attn_kernel(
    const _Float16* __restrict__ u16, const float* __restrict__ wv,
    const float* __restrict__ v, float* __restrict__ attn) {
    const int tc = blockIdx.x, b = blockIdx.y;
    const int tid = threadIdx.x;
    __shared__ float wL[256], vL[256], sc[160], red[2];
    vL[tid] = v[tid];
    for (int ti = 0; ti < 10; ++ti) {
        int t = tc * 10 + ti;
        wL[tid] = wv[(size_t)(b * 300 + t) * 256 + tid];
        __syncthreads();
        float acc = 0.0f;
        if (tid < 160) {
            const uint32_t* ur = (const uint32_t*)(u16 + (size_t)(b * 160 + tid) * 256);
#pragma unroll 8
            for (int e2 = 0; e2 < 128; ++e2) {
                union { uint32_t uu; _Float16 hh[2]; } cv;
                cv.uu = ur[e2];
                int e = e2 * 2;
                acc += vL[e] * ftanh(wL[e] + (float)cv.hh[0]);
                acc += vL[e + 1] * ftanh(wL[e + 1] + (float)cv.hh[1]);
            }
            sc[tid] = acc;
        }
        __syncthreads();
        if (tid < 64) {
            float m = -3.0e38f;
            for (int i = tid; i < 160; i += 64) m = fmaxf(m, sc[i]);
#pragma unroll
            for (int o = 32; o; o >>= 1) m = fmaxf(m, __shfl_xor(m, o));
            if (tid == 0) red[0] = m;
        }
        __syncthreads();
        float ee = 0.0f;
        if (tid < 160) {
            ee = fexp2((acc - red[0]) * 1.4426950408889634f);
            sc[tid] = ee;
        }
        __syncthreads();
        if (tid < 64) {
            float s = 0.0f;
            for (int i = tid; i < 160; i += 64) s += sc[i];
#pragma unroll
            for (int o = 32; o; o >>= 1) s += __shfl_xor(s, o);
            if (tid == 0) red[1] = s;
        }
        __syncthreads();
        if (tid < 160)
            attn[(size_t)(b * 300 + t) * 160 + tid] = ee * frcp(red[1]);
        __syncthreads();
    }
}

// ---------------------------------------------------------------------------
// ws layout (bytes):
//   [0, 7372800)        gi f32 [(t*8+b)*768 + col]           (live: K1b..gru)
//   [7372800, 7766016)  wd u32 dot2-weights [i*1024+t]       (live: prep..gru)
//   [0, 655360)         u f16 [b*160+x][256]   (aliases dead gi, post-gru)
//   [655360, 3112960)   w f32 [b*300+t][256]   (aliases dead gi, post-gru)
// ---------------------------------------------------------------------------
extern "C" void kernel_launch(void* const* d_in, const int* in_sizes, int n_in,
                              void* d_out, int out_size, void* d_ws, size_t ws_size,
                              hipStream_t stream) {
    const float* inputs = (const float*)d_in[0];
    const float* memory = (const float*)d_in[1];
    const float* h0 = (const float*)d_in[2];
    const float* Wih = (const float*)d_in[3];
    const float* Whh = (const float*)d_in[4];
    const float* bih = (const float*)d_in[5];
    const float* bhh = (const float*)d_in[6];
    const float* Wm = (const float*)d_in[7];
    const float* Um = (const float*)d_in[8];
    const float* vv = (const float*)d_in[9];

    float* out = (float*)d_out;
    float* out_attn = out;              // 384000
    float* out_outputs = out + 384000;  // 614400
    float* out_hidden = out + 998400;   // 2048

    char* ws = (char*)d_ws;
    float* gi = (float*)ws;
    unsigned* wd = (unsigned*)(ws + 7372800);
    _Float16* u16 = (_Float16*)ws;
    float* wbuf = (float*)(ws + 655360);

    // Phase 1: weight repack + gi GEMM (bias-folded, scattered)
    prep_wd<<<384, 256, 0, stream>>>(Whh, wd);
    gemm_kernel<<<dim3(12, 38), 256, 0, stream>>>(inputs, Wih, gi, nullptr,
                                                  bih, bhh, 2400, 768, 128, 1);
    // Phase 2: sequential GRU (critical path, 8 CUs, weight-stationary dot2)
    gru_kernel<<<8, 1024, 0, stream>>>(gi, wd, h0, bhh, out_outputs, out_hidden);
    // Phase 3: attention precompute + scores/softmax
    gemm_kernel<<<dim3(4, 20), 256, 0, stream>>>(memory, Um, nullptr, u16,
                                                 nullptr, nullptr, 1280, 256, 256, 2);
    gemm_kernel<<<dim3(4, 38), 256, 0, stream>>>(out_outputs, Wm, wbuf, nullptr,
                                                 nullptr, nullptr, 2400, 256, 256, 0);
    attn_kernel<<<dim3(30, 8), 256, 0, stream>>>(u16, wbuf, vv, out_attn);
}

// Round 6
// 662.863 us; speedup vs baseline: 1.0158x; 1.0158x over previous
//
#include <hip/hip_runtime.h>

// Problem constants
// N=8, T_y=300, T_x=160, E=256, E/2=128, 3E=768
// d_out: [attn 8*300*160 = 384000][outputs 8*300*256 = 614400][hidden 2048]

typedef _Float16 f16x2 __attribute__((ext_vector_type(2)));
typedef _Float16 f16x8 __attribute__((ext_vector_type(8)));

__device__ __forceinline__ float fexp2(float x) { return __builtin_amdgcn_exp2f(x); }
__device__ __forceinline__ float frcp(float x) { return __builtin_amdgcn_rcpf(x); }
// sigmoid(x) = 1/(1+2^(-x*log2 e))
__device__ __forceinline__ float fsig(float x) {
    return frcp(1.0f + fexp2(x * -1.4426950408889634f));
}
// tanh(y) = 1 - 2/(1+2^(y*2*log2 e)); saturates correctly at +-inf args
__device__ __forceinline__ float ftanh(float x) {
    return 1.0f - 2.0f * frcp(1.0f + fexp2(x * 2.8853900817779268f));
}

__device__ __forceinline__ f16x2 bc_h2(unsigned u) {
    union { unsigned u; f16x2 h; } cv;
    cv.u = u;
    return cv.h;
}

// Permuted LDS index for hidden unit j: cc-major so that a quad's four
// k-quarter chunks for the same cc land in different banks.
// j = qi*64 + cc*8 + off  ->  phys = cc*32 + qi*8 + off.
__device__ __forceinline__ int hperm(int j) {
    return ((j >> 3) & 7) * 32 + (j >> 6) * 8 + (j & 7);
}

// ---------------------------------------------------------------------------
// Kernel A: repack Whh (f32 [768][256]) into per-thread v_dot2 weight order.
// gru thread t (of 1024): quad qd=t>>2 owns hidden unit qd's three gate rows
// {qd, qd+256, qd+512}; lane qi=t&3 owns k-quarter [qi*64, qi*64+64).
// Consumption order i = cc*12 + rr*4 + m, cc in [0,8): chunk of 8 f16 at
// k = qi*64 + cc*8; rr = gate row; m = f16x2 within chunk (k+2m).
// wd layout [i*1024 + t] so the one-time gru load is coalesced.
// ---------------------------------------------------------------------------
__global__ __launch_bounds__(256) void prep_wd(const float* __restrict__ Whh,
                                               unsigned* __restrict__ wd) {
    int gid = blockIdx.x * 256 + threadIdx.x;   // 0..98303 = 96*1024
    int i = gid >> 10, t = gid & 1023;
    int qd = t >> 2, qi = t & 3;
    int cc = i / 12, rem = i - cc * 12;
    int rr = rem >> 2, m = rem & 3;
    int row = qd + rr * 256;
    int k = qi * 64 + cc * 8 + 2 * m;
    union { unsigned u; f16x2 h; } cv;
    cv.h[0] = (_Float16)Whh[(size_t)row * 256 + k];
    cv.h[1] = (_Float16)Whh[(size_t)row * 256 + k + 1];
    wd[i * 1024 + t] = cv.u;
}

// ---------------------------------------------------------------------------
// Kernel B: generic f32 tiled GEMM  C[M,N] = X[M,K] @ Wt[N,K]^T
// mode 0: C f32 natural [row*N+col]
// mode 1: gi scatter: row=(b*300+t) -> store at (t*8+b)*768+col, bias folded
//         (bih+bhh for r,z gates; bih only for n gate)
// mode 2: C16 f16 natural
// BM=BN=64, BK=32, 256 threads, 4x4 per thread.
// ---------------------------------------------------------------------------
__global__ __launch_bounds__(256) void gemm_kernel(
    const float* __restrict__ X, const float* __restrict__ Wt,
    float* __restrict__ C, _Float16* __restrict__ C16,
    const float* __restrict__ bih, const float* __restrict__ bhh,
    int M, int N, int K, int mode) {
    __shared__ float Xs[32][65];
    __shared__ float Ws2[32][65];
    const int n0 = blockIdx.x * 64, m0 = blockIdx.y * 64;
    const int tid = threadIdx.x;
    const int tx = tid & 15, ty = tid >> 4;
    float acc[4][4] = {};
    for (int k0 = 0; k0 < K; k0 += 32) {
#pragma unroll
        for (int i = 0; i < 8; ++i) {
            int e = tid + i * 256;
            int kk = e & 31, m = e >> 5;
            int row = m0 + m;
            Xs[kk][m] = (row < M) ? X[(size_t)row * K + k0 + kk] : 0.0f;
            Ws2[kk][m] = Wt[(size_t)(n0 + m) * K + k0 + kk];
        }
        __syncthreads();
#pragma unroll
        for (int kk = 0; kk < 32; ++kk) {
            float a[4], b[4];
#pragma unroll
            for (int i = 0; i < 4; ++i) a[i] = Xs[kk][ty * 4 + i];
#pragma unroll
            for (int j = 0; j < 4; ++j) b[j] = Ws2[kk][tx * 4 + j];
#pragma unroll
            for (int i = 0; i < 4; ++i)
#pragma unroll
                for (int j = 0; j < 4; ++j) acc[i][j] += a[i] * b[j];
        }
        __syncthreads();
    }
#pragma unroll
    for (int i = 0; i < 4; ++i) {
        int row = m0 + ty * 4 + i;
        if (row >= M) continue;
#pragma unroll
        for (int j = 0; j < 4; ++j) {
            int col = n0 + tx * 4 + j;
            float val = acc[i][j];
            if (mode == 1) {
                int b = row / 300;
                int t = row - b * 300;
                val += (col < 512) ? (bih[col] + bhh[col]) : bih[col];
                C[(size_t)(t * 8 + b) * 768 + col] = val;
            } else if (mode == 2) {
                C16[(size_t)row * N + col] = (_Float16)val;
            } else {
                C[(size_t)row * N + col] = val;
            }
        }
    }
}

// ---------------------------------------------------------------------------
// Kernel C: GRU recurrence via v_dot2_f32_f16, weights resident in VGPRs.
// 8 blocks (one per batch) x 1024 threads (16 waves = 4 waves/EU, VGPR cap
// 128; 96 weight words + ~20 temps fit).
// CRITICAL #1: cp loop fully unrolled -> compile-time w[] indices (round 2).
// CRITICAL #2: the empty asm "+v" pin below. Without it the weight loads are
// invariant-marked and LLVM's RA REMATERIALIZES them inside the step loop
// instead of keeping them live (rounds 1/3/4/5: VGPR 124/116/116/64, i.e.
// weights streamed from L2 every step, ~2700-3400 cy/step vs 768 floor).
// The asm makes each word an opaque non-remat VGPR def.
// Quad qd = t>>2 owns hidden unit qd's rows {qd, qd+256, qd+512}; lane
// qi = t&3 owns k-quarter [qi*64,+64). 2-step shfl_xor butterfly -> every
// lane holds (gh_r, gh_z, gh_n) -> in-register epilogue, ONE barrier/step.
// h in LDS f16 double-buffered, hperm layout (bank-conflict-free, verified
// round 5: SQ_LDS_BANK_CONFLICT 1.23M -> 64).
// Issue floor: 96 dot2 x 4 waves x 2cy = 768 cy/SIMD/step.
// ---------------------------------------------------------------------------
__global__ __launch_bounds__(1024)
__attribute__((amdgpu_waves_per_eu(4, 4)))
void gru_kernel(
    const float* __restrict__ gi, const unsigned* __restrict__ wd,
    const float* __restrict__ h0, const float* __restrict__ bhh,
    float* __restrict__ outs, float* __restrict__ hid) {
    const int b = blockIdx.x;
    const int t = threadIdx.x;
    const int qd = t >> 2, qi = t & 3;

    __shared__ __align__(16) _Float16 hbuf[2][256];

    // One-time resident weight load (coalesced): 96 VGPRs/thread.
    unsigned w[96];
#pragma unroll
    for (int i = 0; i < 96; ++i) w[i] = wd[i * 1024 + t];
    // Pin: defeat invariant-load rematerialization (see CRITICAL #2).
#pragma unroll
    for (int i = 0; i < 96; ++i) asm volatile("" : "+v"(w[i]));

    float h = h0[b * 256 + qd];
    const float bn = bhh[512 + qd];   // bhh_n stays inside r*(.)
    const int ph = hperm(qd);
    if (t < 256) hbuf[0][hperm(t)] = (_Float16)h0[b * 256 + t];

    const float* gp = gi + b * 768 + qd;
    float* op = outs + (size_t)b * 76800 + qd;
    __syncthreads();

    for (int st = 0; st < 300; ++st) {
        // gi prefetch (independent of dot2 chain; scheduled early)
        const float* g = gp + (size_t)st * 6144;
        float gr = g[0], gz = g[256], gn = g[512];

        const _Float16* hb = hbuf[st & 1];
        float s0 = 0.f, s1 = 0.f, s2 = 0.f;
#pragma unroll
        for (int cc = 0; cc < 8; ++cc) {
            f16x8 hv = *(const f16x8*)(hb + cc * 32 + qi * 8);  // bank-disjoint
            f16x2 p0 = {hv[0], hv[1]}, p1 = {hv[2], hv[3]};
            f16x2 p2 = {hv[4], hv[5]}, p3 = {hv[6], hv[7]};
            s0 = __builtin_amdgcn_fdot2(bc_h2(w[cc * 12 + 0]), p0, s0, false);
            s0 = __builtin_amdgcn_fdot2(bc_h2(w[cc * 12 + 1]), p1, s0, false);
            s0 = __builtin_amdgcn_fdot2(bc_h2(w[cc * 12 + 2]), p2, s0, false);
            s0 = __builtin_amdgcn_fdot2(bc_h2(w[cc * 12 + 3]), p3, s0, false);
            s1 = __builtin_amdgcn_fdot2(bc_h2(w[cc * 12 + 4]), p0, s1, false);
            s1 = __builtin_amdgcn_fdot2(bc_h2(w[cc * 12 + 5]), p1, s1, false);
            s1 = __builtin_amdgcn_fdot2(bc_h2(w[cc * 12 + 6]), p2, s1, false);
            s1 = __builtin_amdgcn_fdot2(bc_h2(w[cc * 12 + 7]), p3, s1, false);
            s2 = __builtin_amdgcn_fdot2(bc_h2(w[cc * 12 + 8]), p0, s2, false);
            s2 = __builtin_amdgcn_fdot2(bc_h2(w[cc * 12 + 9]), p1, s2, false);
            s2 = __builtin_amdgcn_fdot2(bc_h2(w[cc * 12 + 10]), p2, s2, false);
            s2 = __builtin_amdgcn_fdot2(bc_h2(w[cc * 12 + 11]), p3, s2, false);
        }
        // Quad butterfly: total over the four k-quarters.
        s0 += __shfl_xor(s0, 1); s0 += __shfl_xor(s0, 2);
        s1 += __shfl_xor(s1, 1); s1 += __shfl_xor(s1, 2);
        s2 += __shfl_xor(s2, 1); s2 += __shfl_xor(s2, 2);
        // In-register epilogue (all 4 quad lanes redundantly).
        float r = fsig(gr + s0);
        float z = fsig(gz + s1);
        float n = ftanh(gn + r * (s2 + bn));
        h = n + z * (h - n);
        if (qi == 0) hbuf[(st + 1) & 1][ph] = (_Float16)h;
        else if (qi == 1) op[st * 256] = h;
        __syncthreads();
    }
    if (qi == 2) hid[b * 256 + qd] = h;
}

// ---------------------------------------------------------------------------
// Kernel D: scores + softmax. Block = (t-chunk of 10, batch). Threads 0..159
// each own one x; u read as f16 from ws, w-row and v staged in LDS.
// ---------------------------------------------------------------------------
__global__ __launch_bounds__(256) void attn_kernel(
    const _Float16* __restrict__ u16, const float* __restrict__ wv,
    const float* __restrict__ v, float* __restrict__ attn) {
    const int tc = blockIdx.x, b = blockIdx.y;
    const int tid = threadIdx.x;
    __shared__ float wL[256], vL[256], sc[160], red[2];
    vL[tid] = v[tid];
    for (int ti = 0; ti < 10; ++ti) {
        int t = tc * 10 + ti;
        wL[tid] = wv[(size_t)(b * 300 + t) * 256 + tid];
        __syncthreads();
        float acc = 0.0f;
        if (tid < 160) {
            const uint32_t* ur = (const uint32_t*)(u16 + (size_t)(b * 160 + tid) * 256);
#pragma unroll 8
            for (int e2 = 0; e2 < 128; ++e2) {
                union { uint32_t uu; _Float16 hh[2]; } cv;
                cv.uu = ur[e2];
                int e = e2 * 2;
                acc += vL[e] * ftanh(wL[e] + (float)cv.hh[0]);
                acc += vL[e + 1] * ftanh(wL[e + 1] + (float)cv.hh[1]);
            }
            sc[tid] = acc;
        }
        __syncthreads();
        if (tid < 64) {
            float m = -3.0e38f;
            for (int i = tid; i < 160; i += 64) m = fmaxf(m, sc[i]);
#pragma unroll
            for (int o = 32; o; o >>= 1) m = fmaxf(m, __shfl_xor(m, o));
            if (tid == 0) red[0] = m;
        }
        __syncthreads();
        float ee = 0.0f;
        if (tid < 160) {
            ee = fexp2((acc - red[0]) * 1.4426950408889634f);
            sc[tid] = ee;
        }
        __syncthreads();
        if (tid < 64) {
            float s = 0.0f;
            for (int i = tid; i < 160; i += 64) s += sc[i];
#pragma unroll
            for (int o = 32; o; o >>= 1) s += __shfl_xor(s, o);
            if (tid == 0) red[1] = s;
        }
        __syncthreads();
        if (tid < 160)
            attn[(size_t)(b * 300 + t) * 160 + tid] = ee * frcp(red[1]);
        __syncthreads();
    }
}

// ---------------------------------------------------------------------------
// ws layout (bytes):
//   [0, 7372800)        gi f32 [(t*8+b)*768 + col]           (live: K1b..gru)
//   [7372800, 7766016)  wd u32 dot2-weights [i*1024+t]       (live: prep..gru)
//   [0, 655360)         u f16 [b*160+x][256]   (aliases dead gi, post-gru)
//   [655360, 3112960)   w f32 [b*300+t][256]   (aliases dead gi, post-gru)
// ---------------------------------------------------------------------------
extern "C" void kernel_launch(void* const* d_in, const int* in_sizes, int n_in,
                              void* d_out, int out_size, void* d_ws, size_t ws_size,
                              hipStream_t stream) {
    const float* inputs = (const float*)d_in[0];
    const float* memory = (const float*)d_in[1];
    const float* h0 = (const float*)d_in[2];
    const float* Wih = (const float*)d_in[3];
    const float* Whh = (const float*)d_in[4];
    const float* bih = (const float*)d_in[5];
    const float* bhh = (const float*)d_in[6];
    const float* Wm = (const float*)d_in[7];
    const float* Um = (const float*)d_in[8];
    const float* vv = (const float*)d_in[9];

    float* out = (float*)d_out;
    float* out_attn = out;              // 384000
    float* out_outputs = out + 384000;  // 614400
    float* out_hidden = out + 998400;   // 2048

    char* ws = (char*)d_ws;
    float* gi = (float*)ws;
    unsigned* wd = (unsigned*)(ws + 7372800);
    _Float16* u16 = (_Float16*)ws;
    float* wbuf = (float*)(ws + 655360);

    // Phase 1: weight repack + gi GEMM (bias-folded, scattered)
    prep_wd<<<384, 256, 0, stream>>>(Whh, wd);
    gemm_kernel<<<dim3(12, 38), 256, 0, stream>>>(inputs, Wih, gi, nullptr,
                                                  bih, bhh, 2400, 768, 128, 1);
    // Phase 2: sequential GRU (critical path, 8 CUs, weight-stationary dot2)
    gru_kernel<<<8, 1024, 0, stream>>>(gi, wd, h0, bhh, out_outputs, out_hidden);
    // Phase 3: attention precompute + scores/softmax
    gemm_kernel<<<dim3(4, 20), 256, 0, stream>>>(memory, Um, nullptr, u16,
                                                 nullptr, nullptr, 1280, 256, 256, 2);
    gemm_kernel<<<dim3(4, 38), 256, 0, stream>>>(out_outputs, Wm, wbuf, nullptr,
                                                 nullptr, nullptr, 2400, 256, 256, 0);
    attn_kernel<<<dim3(30, 8), 256, 0, stream>>>(u16, wbuf, vv, out_attn);
}